// Round 7
// baseline (164.407 us; speedup 1.0000x reference)
//
#include <hip/hip_runtime.h>
#include <hip/hip_cooperative_groups.h>

namespace cg = cooperative_groups;

// MinibatchDiscrimination:
//   A: xpT[s][kd][i] = partial (inputs @ T)^T   split-K 8, 64x64 tiles (512 blocks)
//   B: xT[kd][i] = log2e * sum_s xpT[s][kd][i]
//   C: out[i,k] = sum_j exp2(-sum_d |xT[k5+d][i]-xT[k5+d][j]|)  R=4 i/thread
// Single cooperative kernel (512 blocks x 256 thr, 2/CU) when supported;
// otherwise the same phases as 3 standalone kernels.
//
// inputs [512,1024] f32, T [1024,500] f32, out [512,100] f32.

#define BB 512
#define FF 1024
#define KK 100
#define KD 500
#define KDP 512
#define SPLITS 8
#define FN (FF / SPLITS)   // 128 f per split
#define STEPS (FN / 16)    // 8
#define LOG2E 1.4426950408889634f
#define NBLK 512
#define SMEM_FLOATS 5120   // phase A: 2112 used; phase C: 5120 used

// ---------------- Phase A: split-K GEMM tile, transposed store ------------
__device__ __forceinline__ void phaseA(
    int b, int t, const float* __restrict__ in, const float* __restrict__ T,
    float* __restrict__ xpT, float* smem)
{
    float (*Ads)[68] = (float(*)[68])smem;            // [16][68]
    float (*Bds)[64] = (float(*)[64])(smem + 1088);   // [16][64]

    const int i0  = (b & 7) * 64;
    const int kd0 = ((b >> 3) & 7) * 64;
    const int s   = b >> 6;                // 0..7
    const int tk  = t & 15;
    const int ti  = t >> 4;

    float acc[4][4];
    #pragma unroll
    for (int r = 0; r < 4; ++r)
        #pragma unroll
        for (int c = 0; c < 4; ++c) acc[r][c] = 0.f;

    const int ia  = t >> 2;
    const int fqa = t & 3;
    const int kb  = t & 63;
    const int frb = t >> 6;
    const int kbc = min(kd0 + kb, KD - 1);

    const float* inb = in + (size_t)(i0 + ia) * FF + s * FN;
    const float* Tb  = T + (size_t)(s * FN) * KD + kbc;

    float4 av = *(const float4*)&inb[fqa * 4];
    float bv0 = Tb[(size_t)(frb * 4 + 0) * KD];
    float bv1 = Tb[(size_t)(frb * 4 + 1) * KD];
    float bv2 = Tb[(size_t)(frb * 4 + 2) * KD];
    float bv3 = Tb[(size_t)(frb * 4 + 3) * KD];

    for (int step = 0; step < STEPS; ++step) {
        Ads[fqa * 4 + 0][ia] = av.x;
        Ads[fqa * 4 + 1][ia] = av.y;
        Ads[fqa * 4 + 2][ia] = av.z;
        Ads[fqa * 4 + 3][ia] = av.w;
        Bds[frb * 4 + 0][kb] = bv0;
        Bds[frb * 4 + 1][kb] = bv1;
        Bds[frb * 4 + 2][kb] = bv2;
        Bds[frb * 4 + 3][kb] = bv3;
        __syncthreads();

        if (step + 1 < STEPS) {            // prefetch next step under the FMAs
            const int fo = (step + 1) * 16;
            av  = *(const float4*)&inb[fo + fqa * 4];
            bv0 = Tb[(size_t)(fo + frb * 4 + 0) * KD];
            bv1 = Tb[(size_t)(fo + frb * 4 + 1) * KD];
            bv2 = Tb[(size_t)(fo + frb * 4 + 2) * KD];
            bv3 = Tb[(size_t)(fo + frb * 4 + 3) * KD];
        }

        #pragma unroll
        for (int f = 0; f < 16; ++f) {
            float4 a  = *(const float4*)&Ads[f][ti * 4];
            float4 bq = *(const float4*)&Bds[f][tk * 4];
            float ar[4] = {a.x, a.y, a.z, a.w};
            float br[4] = {bq.x, bq.y, bq.z, bq.w};
            #pragma unroll
            for (int r = 0; r < 4; ++r)
                #pragma unroll
                for (int c = 0; c < 4; ++c)
                    acc[r][c] = fmaf(ar[r], br[c], acc[r][c]);
        }
        __syncthreads();
    }

    #pragma unroll
    for (int c = 0; c < 4; ++c) {
        float4 v = {acc[0][c], acc[1][c], acc[2][c], acc[3][c]};
        *(float4*)&xpT[((size_t)s * KDP + kd0 + tk * 4 + c) * BB + i0 + ti * 4] = v;
    }
}

// ---------------- Phase B: fold splits + scale (float2 per thread) --------
__device__ __forceinline__ void phaseB(
    int b, int t, const float* __restrict__ xpT, float* __restrict__ xT)
{
    const int e2 = b * 256 + t;            // float2 index < 131072
    const float2* p2 = (const float2*)xpT;
    float2 v = p2[e2];
    #pragma unroll
    for (int s = 1; s < SPLITS; ++s) {
        float2 w = p2[(size_t)s * (KDP * BB / 2) + e2];
        v.x += w.x; v.y += w.y;
    }
    v.x *= LOG2E; v.y *= LOG2E;
    ((float2*)xT)[e2] = v;
}

// ---------------- Phase C: pairwise exp2(-L1), R=4 i-rows per thread ------
// b in [0,200): k = b>>1, i-half = (b&1)*256. Wave w: j in [w*128,(w+1)*128).
__device__ __forceinline__ void phaseC(
    int b, int t, const float* __restrict__ xT, float* __restrict__ out,
    float* smem)
{
    float (*xs)[8] = (float(*)[8])smem;    // [512][8] = 16 KiB
    float* ps = smem + 4096;               // [4][256]

    const int k    = b >> 1;
    const int ib   = (b & 1) * 256;
    const int lane = t & 63;
    const int w    = t >> 6;

    #pragma unroll
    for (int d = 0; d < 5; ++d) {          // coalesced row reads from xT
        xs[t][d]       = xT[(size_t)(k * 5 + d) * BB + t];
        xs[t + 256][d] = xT[(size_t)(k * 5 + d) * BB + t + 256];
    }
    __syncthreads();

    float xi[4][5];
    #pragma unroll
    for (int r = 0; r < 4; ++r) {
        const int i = ib + r * 64 + lane;
        #pragma unroll
        for (int d = 0; d < 5; ++d) xi[r][d] = xs[i][d];
    }

    float acc[4] = {0.f, 0.f, 0.f, 0.f};
    const int j0 = w << 7;
    #pragma unroll 2
    for (int jj = 0; jj < 128; ++jj) {
        const int j = j0 + jj;             // wave-uniform -> LDS broadcast
        float4 xj0 = *(const float4*)&xs[j][0];
        float  xj4 = xs[j][4];
        #pragma unroll
        for (int r = 0; r < 4; ++r) {
            float aa = (fabsf(xi[r][0] - xj0.x) + fabsf(xi[r][1] - xj0.y))
                     + (fabsf(xi[r][2] - xj0.z) + fabsf(xi[r][3] - xj0.w))
                     + fabsf(xi[r][4] - xj4);
            acc[r] += __builtin_amdgcn_exp2f(-aa);
        }
    }

    #pragma unroll
    for (int r = 0; r < 4; ++r) ps[w * 256 + r * 64 + lane] = acc[r];
    __syncthreads();

    // t covers i_local = t (0..255)
    float v = (ps[t] + ps[256 + t]) + (ps[512 + t] + ps[768 + t]);
    out[(size_t)(ib + t) * KK + k] = v;
}

// ---------------- cooperative fused kernel ----------------
__global__ __launch_bounds__(256, 2) void mbd_coop(
    const float* __restrict__ in, const float* __restrict__ T,
    float* __restrict__ xpT, float* __restrict__ xT, float* __restrict__ out)
{
    __shared__ __align__(16) float smem[SMEM_FLOATS];
    cg::grid_group grid = cg::this_grid();
    const int b = blockIdx.x;
    const int t = threadIdx.x;

    phaseA(b, t, in, T, xpT, smem);
    grid.sync();
    phaseB(b, t, xpT, xT);
    grid.sync();
    __syncthreads();                 // smem handoff A-layout -> C-layout
    if (b < 200) phaseC(b, t, xT, out, smem);
}

// ---------------- standalone fallbacks (same phases) ----------------
__global__ __launch_bounds__(256, 2) void kA(
    const float* __restrict__ in, const float* __restrict__ T,
    float* __restrict__ xpT)
{
    __shared__ __align__(16) float smem[2112];
    phaseA(blockIdx.x, threadIdx.x, in, T, xpT, smem);
}

__global__ __launch_bounds__(256) void kB(
    const float* __restrict__ xpT, float* __restrict__ xT)
{
    phaseB(blockIdx.x, threadIdx.x, xpT, xT);
}

__global__ __launch_bounds__(256) void kC(
    const float* __restrict__ xT, float* __restrict__ out)
{
    __shared__ __align__(16) float smem[SMEM_FLOATS];
    phaseC(blockIdx.x, threadIdx.x, xT, out, smem);
}

// ---------------- last-resort fallback (ws too small) ----------------
__global__ __launch_bounds__(1024, 1) void mbd_fused(
    const float* __restrict__ in, const float* __restrict__ T, float* __restrict__ out)
{
    const int k = blockIdx.x;
    const int t = threadIdx.x;
    const int i = t & (BB - 1);
    const int h = t >> 9;

    __shared__ float xk[1024][8];

    float a0 = 0.f, a1 = 0.f, a2 = 0.f, a3 = 0.f, a4 = 0.f;
    const float4* inrow = (const float4*)(in + (size_t)i * FF + (size_t)h * 512);
    const float* Tk = T + 5 * k + (size_t)h * 512 * KD;

    for (int ff = 0; ff < 512; ff += 4) {
        float4 v = inrow[ff >> 2];
        const float* tp = Tk + (size_t)ff * KD;
        a0 = fmaf(v.x, tp[0], a0); a1 = fmaf(v.x, tp[1], a1); a2 = fmaf(v.x, tp[2], a2);
        a3 = fmaf(v.x, tp[3], a3); a4 = fmaf(v.x, tp[4], a4); tp += KD;
        a0 = fmaf(v.y, tp[0], a0); a1 = fmaf(v.y, tp[1], a1); a2 = fmaf(v.y, tp[2], a2);
        a3 = fmaf(v.y, tp[3], a3); a4 = fmaf(v.y, tp[4], a4); tp += KD;
        a0 = fmaf(v.z, tp[0], a0); a1 = fmaf(v.z, tp[1], a1); a2 = fmaf(v.z, tp[2], a2);
        a3 = fmaf(v.z, tp[3], a3); a4 = fmaf(v.z, tp[4], a4); tp += KD;
        a0 = fmaf(v.w, tp[0], a0); a1 = fmaf(v.w, tp[1], a1); a2 = fmaf(v.w, tp[2], a2);
        a3 = fmaf(v.w, tp[3], a3); a4 = fmaf(v.w, tp[4], a4);
    }
    xk[t][0] = a0; xk[t][1] = a1; xk[t][2] = a2; xk[t][3] = a3; xk[t][4] = a4;
    __syncthreads();
    if (t < BB) {
        xk[t][0] += xk[t + BB][0]; xk[t][1] += xk[t + BB][1]; xk[t][2] += xk[t + BB][2];
        xk[t][3] += xk[t + BB][3]; xk[t][4] += xk[t + BB][4];
    }
    __syncthreads();

    const int jg = t >> 9;
    const float4 xiv = *(const float4*)&xk[i][0];
    const float xi4 = xk[i][4];
    float s0 = 0.f;
    const int j0 = jg << 8;
    for (int jj = 0; jj < 256; ++jj) {
        const int j = j0 + jj;
        float4 xj = *(const float4*)&xk[j][0];
        float xj4 = xk[j][4];
        float aa = (fabsf(xiv.x - xj.x) + fabsf(xiv.y - xj.y))
                 + (fabsf(xiv.z - xj.z) + fabsf(xiv.w - xj.w)) + fabsf(xi4 - xj4);
        s0 += __builtin_amdgcn_exp2f(-1.4426950408889634f * aa);
    }
    xk[BB + i][jg] = s0;
    __syncthreads();
    if (t < BB)
        out[(size_t)t * KK + k] = xk[BB + t][0] + xk[BB + t][1];
}

// ---------------- launch ----------------
extern "C" void kernel_launch(void* const* d_in, const int* in_sizes, int n_in,
                              void* d_out, int out_size, void* d_ws, size_t ws_size,
                              hipStream_t stream) {
    const float* in = (const float*)d_in[0];   // [512, 1024]
    const float* T  = (const float*)d_in[1];   // [1024, 500]
    float* out = (float*)d_out;                // [512, 100]

    const size_t xpT_bytes = (size_t)SPLITS * KDP * BB * sizeof(float);  // 8 MiB
    const size_t xT_bytes  = (size_t)KDP * BB * sizeof(float);           // 1 MiB

    if (ws_size < xpT_bytes + xT_bytes) {
        mbd_fused<<<KK, 1024, 0, stream>>>(in, T, out);
        return;
    }

    float* xpT = (float*)d_ws;
    float* xT  = (float*)((char*)d_ws + xpT_bytes);

    // Host-side capability check (deterministic, capture-safe: no stream ops).
    int dev = 0;
    hipGetDevice(&dev);
    int coopAttr = 0;
    hipDeviceGetAttribute(&coopAttr, hipDeviceAttributeCooperativeLaunch, dev);
    int ncu = 0;
    hipDeviceGetAttribute(&ncu, hipDeviceAttributeMultiprocessorCount, dev);
    int nb = 0;
    hipOccupancyMaxActiveBlocksPerMultiprocessor(&nb, mbd_coop, 256, 0);

    hipError_t st = hipErrorUnknown;
    if (coopAttr && (long)nb * ncu >= NBLK) {
        void* args[] = {(void*)&in, (void*)&T, (void*)&xpT, (void*)&xT, (void*)&out};
        st = hipLaunchCooperativeKernel(reinterpret_cast<void*>(&mbd_coop),
                                        dim3(NBLK), dim3(256), args, 0, stream);
    }
    if (st != hipSuccess) {
        kA<<<NBLK, 256, 0, stream>>>(in, T, xpT);
        kB<<<NBLK, 256, 0, stream>>>(xpT, xT);
        kC<<<200,  256, 0, stream>>>(xT, out);
    }
}

// Round 8
// 35.177 us; speedup vs baseline: 4.6737x; 4.6737x over previous
//
#include <hip/hip_runtime.h>

// MinibatchDiscrimination, two kernels:
//   K1 kA    : xpT[s][kd][i] = partial (inputs @ T)^T  (split-K 8, 64x64 tiles)
//   K2 pairf : fold 8 splits + scale by log2e in LDS fill, then
//              out[i,k] = sum_j exp2(-sum_d |x_i - x_j|)   R=2 i-rows/thread
//
// inputs [512,1024] f32, T [1024,500] f32, out [512,100] f32.

#define BB 512
#define FF 1024
#define KK 100
#define KD 500
#define KDP 512
#define SPLITS 8
#define FN (FF / SPLITS)   // 128 f per split
#define STEPS (FN / 16)    // 8
#define LOG2E 1.4426950408889634f

// ---------------- K1: split-K GEMM tile, transposed partial store ---------
// grid = 512 blocks (8 i-tiles x 8 kd-tiles x 8 splits), block 256, 2/CU.
__global__ __launch_bounds__(256, 2) void kA(
    const float* __restrict__ in, const float* __restrict__ T,
    float* __restrict__ xpT)
{
    __shared__ __align__(16) float smem[2112];
    float (*Ads)[68] = (float(*)[68])smem;            // [16][68]
    float (*Bds)[64] = (float(*)[64])(smem + 1088);   // [16][64]

    const int b = blockIdx.x;
    const int t = threadIdx.x;
    const int i0  = (b & 7) * 64;
    const int kd0 = ((b >> 3) & 7) * 64;
    const int s   = b >> 6;                // 0..7
    const int tk  = t & 15;
    const int ti  = t >> 4;

    float acc[4][4];
    #pragma unroll
    for (int r = 0; r < 4; ++r)
        #pragma unroll
        for (int c = 0; c < 4; ++c) acc[r][c] = 0.f;

    const int ia  = t >> 2;                // i row for A staging
    const int fqa = t & 3;                 // f-quad for A
    const int kb  = t & 63;                // kd lane for B
    const int frb = t >> 6;                // f-quad for B
    const int kbc = min(kd0 + kb, KD - 1);

    const float* inb = in + (size_t)(i0 + ia) * FF + s * FN;
    const float* Tb  = T + (size_t)(s * FN) * KD + kbc;

    float4 av = *(const float4*)&inb[fqa * 4];
    float bv0 = Tb[(size_t)(frb * 4 + 0) * KD];
    float bv1 = Tb[(size_t)(frb * 4 + 1) * KD];
    float bv2 = Tb[(size_t)(frb * 4 + 2) * KD];
    float bv3 = Tb[(size_t)(frb * 4 + 3) * KD];

    for (int step = 0; step < STEPS; ++step) {
        Ads[fqa * 4 + 0][ia] = av.x;
        Ads[fqa * 4 + 1][ia] = av.y;
        Ads[fqa * 4 + 2][ia] = av.z;
        Ads[fqa * 4 + 3][ia] = av.w;
        Bds[frb * 4 + 0][kb] = bv0;
        Bds[frb * 4 + 1][kb] = bv1;
        Bds[frb * 4 + 2][kb] = bv2;
        Bds[frb * 4 + 3][kb] = bv3;
        __syncthreads();

        if (step + 1 < STEPS) {            // prefetch next step under the FMAs
            const int fo = (step + 1) * 16;
            av  = *(const float4*)&inb[fo + fqa * 4];
            bv0 = Tb[(size_t)(fo + frb * 4 + 0) * KD];
            bv1 = Tb[(size_t)(fo + frb * 4 + 1) * KD];
            bv2 = Tb[(size_t)(fo + frb * 4 + 2) * KD];
            bv3 = Tb[(size_t)(fo + frb * 4 + 3) * KD];
        }

        #pragma unroll
        for (int f = 0; f < 16; ++f) {
            float4 a  = *(const float4*)&Ads[f][ti * 4];
            float4 bq = *(const float4*)&Bds[f][tk * 4];
            float ar[4] = {a.x, a.y, a.z, a.w};
            float br[4] = {bq.x, bq.y, bq.z, bq.w};
            #pragma unroll
            for (int r = 0; r < 4; ++r)
                #pragma unroll
                for (int c = 0; c < 4; ++c)
                    acc[r][c] = fmaf(ar[r], br[c], acc[r][c]);
        }
        __syncthreads();
    }

    // transposed store: xpT[s][kd0+tk*4+c][i0+ti*4 .. +3]
    #pragma unroll
    for (int c = 0; c < 4; ++c) {
        float4 v = {acc[0][c], acc[1][c], acc[2][c], acc[3][c]};
        *(float4*)&xpT[((size_t)s * KDP + kd0 + tk * 4 + c) * BB + i0 + ti * 4] = v;
    }
}

// ---------------- K2: fold + pairwise exp2(-L1), R=2 i-rows per thread ----
// grid (100 k, 4 i-parts of 128), block 512 (8 waves).
// Wave w: j in [w*64, (w+1)*64); thread covers i = p*128 + lane and +64.
__global__ __launch_bounds__(512) void pairf(
    const float* __restrict__ xpT, float* __restrict__ out)
{
    const int k = blockIdx.x;
    const int p = blockIdx.y;
    const int t = threadIdx.x;
    const int lane = t & 63;
    const int w    = t >> 6;

    __shared__ float xs[BB][8];     // 16 KiB (32B rows, b128-aligned)
    __shared__ float ps[8][128];    // 4 KiB

    // fill: fold 8 split partials, pre-scale by log2e. Coalesced rows of 512.
    #pragma unroll
    for (int d = 0; d < 5; ++d) {
        float v = 0.f;
        #pragma unroll
        for (int s = 0; s < SPLITS; ++s)
            v += xpT[((size_t)s * KDP + k * 5 + d) * BB + t];
        xs[t][d] = LOG2E * v;
    }
    __syncthreads();

    const int ia = p * 128 + lane;
    float xa[5], xb[5];
    #pragma unroll
    for (int d = 0; d < 5; ++d) { xa[d] = xs[ia][d]; xb[d] = xs[ia + 64][d]; }

    float sa = 0.f, sb = 0.f;
    const int j0 = w << 6;
    #pragma unroll 2
    for (int jj = 0; jj < 64; ++jj) {
        const int j = j0 + jj;             // wave-uniform -> LDS broadcast
        float4 xj0 = *(const float4*)&xs[j][0];
        float  xj4 = xs[j][4];
        float aa = (fabsf(xa[0] - xj0.x) + fabsf(xa[1] - xj0.y))
                 + (fabsf(xa[2] - xj0.z) + fabsf(xa[3] - xj0.w))
                 + fabsf(xa[4] - xj4);
        float bb = (fabsf(xb[0] - xj0.x) + fabsf(xb[1] - xj0.y))
                 + (fabsf(xb[2] - xj0.z) + fabsf(xb[3] - xj0.w))
                 + fabsf(xb[4] - xj4);
        sa += __builtin_amdgcn_exp2f(-aa);
        sb += __builtin_amdgcn_exp2f(-bb);
    }

    ps[w][lane]      = sa;
    ps[w][lane + 64] = sb;
    __syncthreads();

    if (t < 128) {
        float v = 0.f;
        #pragma unroll
        for (int q = 0; q < 8; ++q) v += ps[q][t];
        out[(size_t)(p * 128 + t) * KK + k] = v;
    }
}

// ---------------- last-resort fallback (ws too small) ----------------
__global__ __launch_bounds__(1024, 1) void mbd_fused(
    const float* __restrict__ in, const float* __restrict__ T, float* __restrict__ out)
{
    const int k = blockIdx.x;
    const int t = threadIdx.x;
    const int i = t & (BB - 1);
    const int h = t >> 9;

    __shared__ float xk[1024][8];

    float a0 = 0.f, a1 = 0.f, a2 = 0.f, a3 = 0.f, a4 = 0.f;
    const float4* inrow = (const float4*)(in + (size_t)i * FF + (size_t)h * 512);
    const float* Tk = T + 5 * k + (size_t)h * 512 * KD;

    for (int ff = 0; ff < 512; ff += 4) {
        float4 v = inrow[ff >> 2];
        const float* tp = Tk + (size_t)ff * KD;
        a0 = fmaf(v.x, tp[0], a0); a1 = fmaf(v.x, tp[1], a1); a2 = fmaf(v.x, tp[2], a2);
        a3 = fmaf(v.x, tp[3], a3); a4 = fmaf(v.x, tp[4], a4); tp += KD;
        a0 = fmaf(v.y, tp[0], a0); a1 = fmaf(v.y, tp[1], a1); a2 = fmaf(v.y, tp[2], a2);
        a3 = fmaf(v.y, tp[3], a3); a4 = fmaf(v.y, tp[4], a4); tp += KD;
        a0 = fmaf(v.z, tp[0], a0); a1 = fmaf(v.z, tp[1], a1); a2 = fmaf(v.z, tp[2], a2);
        a3 = fmaf(v.z, tp[3], a3); a4 = fmaf(v.z, tp[4], a4); tp += KD;
        a0 = fmaf(v.w, tp[0], a0); a1 = fmaf(v.w, tp[1], a1); a2 = fmaf(v.w, tp[2], a2);
        a3 = fmaf(v.w, tp[3], a3); a4 = fmaf(v.w, tp[4], a4);
    }
    xk[t][0] = a0; xk[t][1] = a1; xk[t][2] = a2; xk[t][3] = a3; xk[t][4] = a4;
    __syncthreads();
    if (t < BB) {
        xk[t][0] += xk[t + BB][0]; xk[t][1] += xk[t + BB][1]; xk[t][2] += xk[t + BB][2];
        xk[t][3] += xk[t + BB][3]; xk[t][4] += xk[t + BB][4];
    }
    __syncthreads();

    const int jg = t >> 9;
    const float4 xiv = *(const float4*)&xk[i][0];
    const float xi4 = xk[i][4];
    float s0 = 0.f;
    const int j0 = jg << 8;
    for (int jj = 0; jj < 256; ++jj) {
        const int j = j0 + jj;
        float4 xj = *(const float4*)&xk[j][0];
        float xj4 = xk[j][4];
        float aa = (fabsf(xiv.x - xj.x) + fabsf(xiv.y - xj.y))
                 + (fabsf(xiv.z - xj.z) + fabsf(xiv.w - xj.w)) + fabsf(xi4 - xj4);
        s0 += __builtin_amdgcn_exp2f(-1.4426950408889634f * aa);
    }
    xk[BB + i][jg] = s0;
    __syncthreads();
    if (t < BB)
        out[(size_t)t * KK + k] = xk[BB + t][0] + xk[BB + t][1];
}

// ---------------- launch ----------------
extern "C" void kernel_launch(void* const* d_in, const int* in_sizes, int n_in,
                              void* d_out, int out_size, void* d_ws, size_t ws_size,
                              hipStream_t stream) {
    const float* in = (const float*)d_in[0];   // [512, 1024]
    const float* T  = (const float*)d_in[1];   // [1024, 500]
    float* out = (float*)d_out;                // [512, 100]

    const size_t xpT_bytes = (size_t)SPLITS * KDP * BB * sizeof(float);  // 8 MiB

    if (ws_size < xpT_bytes) {
        mbd_fused<<<KK, 1024, 0, stream>>>(in, T, out);
        return;
    }

    float* xpT = (float*)d_ws;

    kA<<<512, 256, 0, stream>>>(in, T, xpT);

    dim3 g2(KK, 4);                    // 400 blocks
    pairf<<<g2, 512, 0, stream>>>(xpT, out);
}